// Round 8
// baseline (258.073 us; speedup 1.0000x reference)
//
#include <hip/hip_runtime.h>
#include <math.h>

#define SS 2048
#define BB 2
#define DD 1024
#define HH 16
#define DKK 64
#define MM (SS*BB)   // 4096

typedef _Float16 f16;
typedef __attribute__((ext_vector_type(8))) _Float16 f16x8;
typedef __attribute__((ext_vector_type(2))) __fp16 fp16x2r;   // cvt_pkrtz / fdot2 type
typedef __attribute__((ext_vector_type(4))) float f32x4;
typedef __attribute__((ext_vector_type(16))) float f32x16;

__device__ __forceinline__ unsigned pk2(float a, float b) {
    union { fp16x2r h; unsigned u; } v;
    v.h = __builtin_amdgcn_cvt_pkrtz(a, b);
    return v.u;
}
__device__ __forceinline__ void gload_lds16(const void* g, void* l) {
    __builtin_amdgcn_global_load_lds(
        (const __attribute__((address_space(1))) unsigned*)g,
        (__attribute__((address_space(3))) unsigned*)l, 16, 0, 0);
}

// ---------------------------------------------------------------------------
// fp32 -> f16, all 7 tensors in one launch.
// ---------------------------------------------------------------------------
__global__ __launch_bounds__(256)
void cvt_all(const float* __restrict__ q, const float* __restrict__ k,
             const float* __restrict__ v, const float* __restrict__ wq,
             const float* __restrict__ wk, const float* __restrict__ wv,
             const float* __restrict__ wo,
             f16* __restrict__ xout, f16* __restrict__ wout)
{
    const int z = blockIdx.y;
    const float* src;
    f16* dst;
    if (z < 3) {
        src = z == 0 ? q : (z == 1 ? k : v);
        dst = xout + (size_t)z*MM*DD;
    } else {
        if (blockIdx.x >= DD*DD/8/256) return;
        src = z == 3 ? wq : (z == 4 ? wk : (z == 5 ? wv : wo));
        dst = wout + (size_t)(z-3)*DD*DD;
    }
    size_t t = (size_t)blockIdx.x*256 + threadIdx.x;
    float4 f0 = ((const float4*)src)[t*2];
    float4 f1 = ((const float4*)src)[t*2+1];
    uint4 r;
    r.x = pk2(f0.x, f0.y); r.y = pk2(f0.z, f0.w);
    r.z = pk2(f1.x, f1.y); r.w = pk2(f1.z, f1.w);
    ((uint4*)dst)[t] = r;
}

// ---------------------------------------------------------------------------
// Batched QKV GEMM, f16, C = A.W^T + bias.  blockIdx.z in {0,1,2} = Q,K,V.
// z==2 epilogue: LDS transpose -> coalesced 16B Vt stores (two n-halves).
// ---------------------------------------------------------------------------
__global__ __launch_bounds__(256)
void qkv_gemm(const f16* __restrict__ A16, const f16* __restrict__ W16,
              const float* __restrict__ bq, const float* __restrict__ bk,
              const float* __restrict__ bv,
              f16* __restrict__ Qh, f16* __restrict__ Kh, f16* __restrict__ Vt)
{
    __shared__ __align__(16) char qsmem[16896];
    f16* const As = (f16*)qsmem;
    f16* const Bs = (f16*)(qsmem + 8192);
    f16* const Ct = (f16*)qsmem;              // [64 d][b*64+s], stride 132 (alias)

    const int tid  = threadIdx.x;
    const int w    = tid >> 6;
    const int lane = tid & 63;
    const int ln   = lane & 15;
    const int quad = lane >> 4;
    const int z  = blockIdx.z;
    const int m0 = blockIdx.x * 128;
    const int n0 = blockIdx.y * 128;
    const int wm = (w >> 1) * 64;
    const int wn = (w & 1) * 64;

    const f16* A = A16 + (size_t)z*MM*DD;
    const f16* W = W16 + (size_t)z*DD*DD;
    const float* bias = z == 0 ? bq : (z == 1 ? bk : bv);

    f32x4 acc[4][4];
    #pragma unroll
    for (int mt = 0; mt < 4; mt++)
        #pragma unroll
        for (int nt = 0; nt < 4; nt++)
            acc[mt][nt] = (f32x4){0.f,0.f,0.f,0.f};

    int slot[2], r_[2], gch[2];
    #pragma unroll
    for (int i = 0; i < 2; i++) {
        slot[i] = i*256 + tid;
        r_[i]   = slot[i] >> 2;
        gch[i]  = ((slot[i] & 3) ^ ((r_[i] >> 1) & 3)) * 8;
    }

    for (int step = 0; step < DD/32; step++) {
        const int k0 = step*32;
        __syncthreads();
        #pragma unroll
        for (int i = 0; i < 2; i++) {
            gload_lds16(A + (size_t)(m0 + r_[i])*DD + k0 + gch[i],
                        (char*)As + slot[i]*16);
            gload_lds16(W + (size_t)(n0 + r_[i])*DD + k0 + gch[i],
                        (char*)Bs + slot[i]*16);
        }
        __syncthreads();

        f16x8 af[4], bf[4];
        #pragma unroll
        for (int mt = 0; mt < 4; mt++) {
            int r = wm + mt*16 + ln;
            af[mt] = *(const f16x8*)&As[r*32 + ((quad ^ ((r>>1)&3)) << 3)];
        }
        #pragma unroll
        for (int nt = 0; nt < 4; nt++) {
            int r = wn + nt*16 + ln;
            bf[nt] = *(const f16x8*)&Bs[r*32 + ((quad ^ ((r>>1)&3)) << 3)];
        }
        #pragma unroll
        for (int mt = 0; mt < 4; mt++)
            #pragma unroll
            for (int nt = 0; nt < 4; nt++)
                acc[mt][nt] = __builtin_amdgcn_mfma_f32_16x16x32_f16(
                    af[mt], bf[nt], acc[mt][nt], 0, 0, 0);
    }

    float bvv[4];
    #pragma unroll
    for (int nt = 0; nt < 4; nt++) bvv[nt] = bias[n0 + wn + nt*16 + ln];

    if (z == 2) {
        // LDS transpose epilogue, one n-half (=head) at a time.
        #pragma unroll
        for (int half = 0; half < 2; half++) {
            __syncthreads();
            if ((wn >> 6) == half) {
                #pragma unroll
                for (int mt = 0; mt < 4; mt++)
                    #pragma unroll
                    for (int nt = 0; nt < 4; nt++)
                        #pragma unroll
                        for (int r = 0; r < 4; r++) {
                            int d = nt*16 + ln;
                            int sl = (wm >> 1) + mt*8 + quad*2 + (r >> 1);
                            Ct[d*132 + (r&1)*64 + sl] =
                                (f16)(acc[mt][nt][r] + bvv[nt]);
                        }
            }
            __syncthreads();
            // readers: 256 thr; t -> d=t>>2, b=(t>>1)&1, seg=t&1 (32 s each)
            {
                int d   = tid >> 2;
                int bb2 = (tid >> 1) & 1;
                int seg = tid & 1;
                int hh  = (n0 >> 6) + half;
                const f16* srcp = &Ct[d*132 + bb2*64 + seg*32];
                f16* dstp = Vt + ((size_t)(bb2*HH + hh)*DKK + d)*SS
                               + (m0 >> 1) + seg*32;
                #pragma unroll
                for (int k2 = 0; k2 < 4; k2++) {
                    uint2 a = *(const uint2*)(srcp + k2*8);
                    uint2 c = *(const uint2*)(srcp + k2*8 + 4);
                    uint4 u; u.x = a.x; u.y = a.y; u.z = c.x; u.w = c.y;
                    *(uint4*)(dstp + k2*8) = u;
                }
            }
        }
    } else {
        const float scale = z == 0 ? 0.125f : 1.0f;
        f16* dst = z == 0 ? Qh : Kh;
        #pragma unroll
        for (int mt = 0; mt < 4; mt++)
            #pragma unroll
            for (int nt = 0; nt < 4; nt++)
                #pragma unroll
                for (int r = 0; r < 4; r++) {
                    int m = m0 + wm + mt*16 + quad*4 + r;
                    int n = n0 + wn + nt*16 + ln;
                    int s = m >> 1, b = m & 1;
                    int h = n >> 6, d = n & 63;
                    dst[(((size_t)(b*HH + h))*SS + s)*DKK + d] =
                        (f16)((acc[mt][nt][r] + bvv[nt]) * scale);
                }
    }
}

// ---------------------------------------------------------------------------
// Output projection (unchanged).
// ---------------------------------------------------------------------------
__global__ __launch_bounds__(256)
void out_gemm(const f16* __restrict__ A, const f16* __restrict__ W,
              const float* __restrict__ bias, float* __restrict__ out)
{
    __shared__ __align__(16) f16 As[64*32];
    __shared__ __align__(16) f16 Bs[128*32];

    const int tid  = threadIdx.x;
    const int w    = tid >> 6;
    const int lane = tid & 63;
    const int ln   = lane & 15;
    const int quad = lane >> 4;
    const int m0 = blockIdx.x * 64;
    const int n0 = blockIdx.y * 128;
    const int wm = (w >> 1) * 32;
    const int wn = (w & 1) * 64;

    f32x4 acc[2][4];
    #pragma unroll
    for (int mt = 0; mt < 2; mt++)
        #pragma unroll
        for (int nt = 0; nt < 4; nt++)
            acc[mt][nt] = (f32x4){0.f,0.f,0.f,0.f};

    const int rA  = tid >> 2;
    const int gchA = ((tid & 3) ^ ((rA >> 1) & 3)) * 8;
    int slotB[2], rB[2], gchB[2];
    #pragma unroll
    for (int i = 0; i < 2; i++) {
        slotB[i] = i*256 + tid;
        rB[i]    = slotB[i] >> 2;
        gchB[i]  = ((slotB[i] & 3) ^ ((rB[i] >> 1) & 3)) * 8;
    }

    for (int step = 0; step < DD/32; step++) {
        const int k0 = step*32;
        __syncthreads();
        gload_lds16(A + (size_t)(m0 + rA)*DD + k0 + gchA, (char*)As + tid*16);
        #pragma unroll
        for (int i = 0; i < 2; i++)
            gload_lds16(W + (size_t)(n0 + rB[i])*DD + k0 + gchB[i],
                        (char*)Bs + slotB[i]*16);
        __syncthreads();

        f16x8 af[2], bf[4];
        #pragma unroll
        for (int mt = 0; mt < 2; mt++) {
            int r = wm + mt*16 + ln;
            af[mt] = *(const f16x8*)&As[r*32 + ((quad ^ ((r>>1)&3)) << 3)];
        }
        #pragma unroll
        for (int nt = 0; nt < 4; nt++) {
            int r = wn + nt*16 + ln;
            bf[nt] = *(const f16x8*)&Bs[r*32 + ((quad ^ ((r>>1)&3)) << 3)];
        }
        #pragma unroll
        for (int mt = 0; mt < 2; mt++)
            #pragma unroll
            for (int nt = 0; nt < 4; nt++)
                acc[mt][nt] = __builtin_amdgcn_mfma_f32_16x16x32_f16(
                    af[mt], bf[nt], acc[mt][nt], 0, 0, 0);
    }

    #pragma unroll
    for (int nt = 0; nt < 4; nt++) {
        float bvv = bias[n0 + wn + nt*16 + ln];
        #pragma unroll
        for (int mt = 0; mt < 2; mt++)
            #pragma unroll
            for (int r = 0; r < 4; r++) {
                int m = m0 + wm + mt*16 + quad*4 + r;
                int n = n0 + wn + nt*16 + ln;
                out[(size_t)m*DD + n] = acc[mt][nt][r] + bvv;
            }
    }
}

// ---------------------------------------------------------------------------
// Attention v7: 32x32x16, transposed-score, KV-split x2, P IN REGISTERS.
// C-layout of S^T gives lane (l5,hf) column q=l5, keys split by quad-bit(4hf).
// PV B-frag needs keys split by hf*8 -> exchange 2 u32 with partner (lane^32)
// via __shfl_xor; cndmask arranges {keep,recv} by hf.  Row-sum l via
// v_dot2_f32_f16 on the packed P words (exact wrt pack rounding).
// No P LDS, no ones-MFMA.  LDS 33.8KB; __launch_bounds__(512,6) -> 3 blk/CU.
// ---------------------------------------------------------------------------
__global__ __launch_bounds__(512, 6)
void attn_v7(const f16* __restrict__ Q, const f16* __restrict__ K,
             const f16* __restrict__ V, f16* __restrict__ Xh)
{
    __shared__ __align__(16) char arena[33792];
    float* const Ol = (float*)arena;                 // [128][65] (combine, aliased)
    float* const Ls = (float*)(arena + 33280);       // [128]

    const int tid  = threadIdx.x;
    const int g    = tid >> 8;         // kv-split group
    const int wg   = tid >> 6;
    const int w4   = wg & 3;
    const int lane = tid & 63;
    const int l5   = lane & 31;
    const int hf   = lane >> 5;
    const int h = blockIdx.y, b = blockIdx.z;
    const size_t base = ((size_t)(b*HH + h)) * SS * DKK;
    const int Q0 = blockIdx.x * 128;
    const int q  = w4*32 + l5;

    f16x8 qf[4];
    #pragma unroll
    for (int ks = 0; ks < 4; ks++)
        qf[ks] = *(const f16x8*)(Q + base + (size_t)(Q0 + q)*DKK + ks*16 + hf*8);

    f32x16 o[2];
    o[0] = (f32x16)(0.f); o[1] = (f32x16)(0.f);
    float lsum = 0.f;
    fp16x2r one2; one2[0] = (__fp16)1.0f; one2[1] = (__fp16)1.0f;

    const f16* const Ksg = (const f16*)(arena + g*8192);
    const f16* const Vsg = (const f16*)(arena + 16384 + g*8192);

    for (int t = 0; t < 16; t++) {
        __syncthreads();
        #pragma unroll
        for (int i = 0; i < 4; i++) {
            int slot = i*512 + tid;          // 0..2047
            int kv   = slot >> 10;           // 0 K, 1 V
            int s    = (slot >> 9) & 1;      // stream
            int idx  = slot & 511;
            int r    = idx >> 3, c8 = idx & 7;
            int kts  = s*16 + t;
            const f16* src = kv == 0
                ? K + base + (size_t)(kts*64 + r)*DKK + ((c8 ^ (r&7)) << 3)
                : V + base + (size_t)r*SS + kts*64 + ((c8 ^ (r&7)) << 3);
            gload_lds16(src, arena + kv*16384 + s*8192 + idx*16);
        }
        __syncthreads();

        // ---- S^T = K @ Q^T, per mt pass; exp + pack + row-sum ----
        unsigned U[2][4][2];
        #pragma unroll
        for (int mt = 0; mt < 2; mt++) {
            f32x16 sc = (f32x16)(0.f);
            #pragma unroll
            for (int ks = 0; ks < 4; ks++) {
                const int cc = ks*2 + hf;
                int key = mt*32 + l5;
                f16x8 ka = *(const f16x8*)&Ksg[key*64 + ((cc ^ (key&7)) << 3)];
                sc = __builtin_amdgcn_mfma_f32_32x32x16_f16(ka, qf[ks], sc, 0, 0, 0);
            }
            #pragma unroll
            for (int gg = 0; gg < 4; gg++) {
                unsigned u0 = pk2(__expf(sc[gg*4+0]), __expf(sc[gg*4+1]));
                unsigned u1 = pk2(__expf(sc[gg*4+2]), __expf(sc[gg*4+3]));
                U[mt][gg][0] = u0;
                U[mt][gg][1] = u1;
                union { unsigned u; fp16x2r h; } c0, c1;
                c0.u = u0; c1.u = u1;
                lsum = __builtin_amdgcn_fdot2(c0.h, one2, lsum, false);
                lsum = __builtin_amdgcn_fdot2(c1.h, one2, lsum, false);
            }
        }

        // ---- exchange -> PV B-frags; O^T += Vt @ P ----
        #pragma unroll
        for (int ks = 0; ks < 4; ks++) {
            const int mt0 = ks >> 1;
            const int e   = (ks & 1) * 2;
            unsigned k0 = hf ? U[mt0][e+1][0] : U[mt0][e][0];
            unsigned k1 = hf ? U[mt0][e+1][1] : U[mt0][e][1];
            unsigned s0 = hf ? U[mt0][e][0]   : U[mt0][e+1][0];
            unsigned s1 = hf ? U[mt0][e][1]   : U[mt0][e+1][1];
            unsigned r0 = __shfl_xor(s0, 32, 64);
            unsigned r1 = __shfl_xor(s1, 32, 64);
            union { unsigned u[4]; f16x8 v; } pbu;
            pbu.u[0] = hf ? r0 : k0;
            pbu.u[1] = hf ? r1 : k1;
            pbu.u[2] = hf ? k0 : r0;
            pbu.u[3] = hf ? k1 : r1;
            f16x8 pb = pbu.v;
            const int cc = ks*2 + hf;
            #pragma unroll
            for (int mt = 0; mt < 2; mt++) {
                int d = mt*32 + l5;
                f16x8 va = *(const f16x8*)&Vsg[d*64 + ((cc ^ (d&7)) << 3)];
                o[mt] = __builtin_amdgcn_mfma_f32_32x32x16_f16(va, pb, o[mt], 0, 0, 0);
            }
        }
    }

    // column total for q over this group's keys (both hf halves)
    float lfull = lsum + __shfl_xor(lsum, 32, 64);

    // ---- combine: g1 parks partials (arena dead), g0 reduces + writes ----
    __syncthreads();
    if (g == 1) {
        #pragma unroll
        for (int mt = 0; mt < 2; mt++)
            #pragma unroll
            for (int reg = 0; reg < 16; reg++) {
                int d = mt*32 + (reg & 3) + 8*(reg >> 2) + 4*hf;
                Ol[q*65 + d] = o[mt][reg];
            }
        if (hf == 0) Ls[q] = lfull;
    }
    __syncthreads();
    if (g == 0) {
        const float inv = 1.0f / (lfull + Ls[q]);
        const int qg = Q0 + q;
        f16* xp = Xh + ((size_t)qg*BB + b)*DD + h*DKK;
        #pragma unroll
        for (int mt = 0; mt < 2; mt++)
            #pragma unroll
            for (int gg = 0; gg < 4; gg++) {
                float v0 = (o[mt][gg*4+0] + Ol[q*65 + mt*32 + 8*gg + 4*hf + 0]) * inv;
                float v1 = (o[mt][gg*4+1] + Ol[q*65 + mt*32 + 8*gg + 4*hf + 1]) * inv;
                float v2 = (o[mt][gg*4+2] + Ol[q*65 + mt*32 + 8*gg + 4*hf + 2]) * inv;
                float v3 = (o[mt][gg*4+3] + Ol[q*65 + mt*32 + 8*gg + 4*hf + 3]) * inv;
                uint2 pk;
                pk.x = pk2(v0, v1);
                pk.y = pk2(v2, v3);
                *(uint2*)&xp[mt*32 + gg*8 + hf*4] = pk;
            }
    }
}

// ---------------------------------------------------------------------------
extern "C" void kernel_launch(void* const* d_in, const int* in_sizes, int n_in,
                              void* d_out, int out_size, void* d_ws, size_t ws_size,
                              hipStream_t stream) {
    (void)in_sizes; (void)n_in; (void)out_size; (void)ws_size;
    const float* query = (const float*)d_in[0];
    const float* key   = (const float*)d_in[1];
    const float* value = (const float*)d_in[2];
    const float* Wq = (const float*)d_in[3];
    const float* bq = (const float*)d_in[4];
    const float* Wk = (const float*)d_in[5];
    const float* bk = (const float*)d_in[6];
    const float* Wv = (const float*)d_in[7];
    const float* bv = (const float*)d_in[8];
    const float* Wo = (const float*)d_in[9];
    const float* bo = (const float*)d_in[10];

    char* ws = (char*)d_ws;
    f16* A16 = (f16*)ws;                          // 3 x 4096x1024 f16
    f16* W16 = (f16*)(ws + 25165824);             // 4 x 1024x1024 f16
    f16* Qh  = (f16*)(ws + 33554432);
    f16* Kh  = (f16*)(ws + 41943040);
    f16* Vt  = (f16*)(ws + 50331648);
    f16* Xh  = (f16*)(ws + 58720256);             // total 64 MiB

    cvt_all<<<dim3(MM*DD/8/256, 7), 256, 0, stream>>>(
        query, key, value, Wq, Wk, Wv, Wo, A16, W16);

    qkv_gemm<<<dim3(MM/128, DD/128, 3), 256, 0, stream>>>(
        A16, W16, bq, bk, bv, Qh, Kh, Vt);

    attn_v7<<<dim3(SS/128, HH, BB), 512, 0, stream>>>(Qh, Kh, Vt, Xh);

    out_gemm<<<dim3(MM/64, DD/128), 256, 0, stream>>>(
        Xh, W16 + (size_t)3*DD*DD, bo, (float*)d_out);
}

// Round 9
// 223.925 us; speedup vs baseline: 1.1525x; 1.1525x over previous
//
#include <hip/hip_runtime.h>
#include <math.h>

#define SS 2048
#define BB 2
#define DD 1024
#define HH 16
#define DKK 64
#define MM (SS*BB)   // 4096

typedef _Float16 f16;
typedef __attribute__((ext_vector_type(8))) _Float16 f16x8;
typedef __attribute__((ext_vector_type(2))) __fp16 fp16x2r;   // cvt_pkrtz / fdot2 type
typedef __attribute__((ext_vector_type(4))) float f32x4;
typedef __attribute__((ext_vector_type(16))) float f32x16;

__device__ __forceinline__ unsigned pk2(float a, float b) {
    union { fp16x2r h; unsigned u; } v;
    v.h = __builtin_amdgcn_cvt_pkrtz(a, b);
    return v.u;
}
__device__ __forceinline__ void gload_lds16(const void* g, void* l) {
    __builtin_amdgcn_global_load_lds(
        (const __attribute__((address_space(1))) unsigned*)g,
        (__attribute__((address_space(3))) unsigned*)l, 16, 0, 0);
}

// ---------------------------------------------------------------------------
// fp32 -> f16, all 7 tensors in one launch.
// ---------------------------------------------------------------------------
__global__ __launch_bounds__(256)
void cvt_all(const float* __restrict__ q, const float* __restrict__ k,
             const float* __restrict__ v, const float* __restrict__ wq,
             const float* __restrict__ wk, const float* __restrict__ wv,
             const float* __restrict__ wo,
             f16* __restrict__ xout, f16* __restrict__ wout)
{
    const int z = blockIdx.y;
    const float* src;
    f16* dst;
    if (z < 3) {
        src = z == 0 ? q : (z == 1 ? k : v);
        dst = xout + (size_t)z*MM*DD;
    } else {
        if (blockIdx.x >= DD*DD/8/256) return;
        src = z == 3 ? wq : (z == 4 ? wk : (z == 5 ? wv : wo));
        dst = wout + (size_t)(z-3)*DD*DD;
    }
    size_t t = (size_t)blockIdx.x*256 + threadIdx.x;
    float4 f0 = ((const float4*)src)[t*2];
    float4 f1 = ((const float4*)src)[t*2+1];
    uint4 r;
    r.x = pk2(f0.x, f0.y); r.y = pk2(f0.z, f0.w);
    r.z = pk2(f1.x, f1.y); r.w = pk2(f1.z, f1.w);
    ((uint4*)dst)[t] = r;
}

// ---------------------------------------------------------------------------
// Batched QKV GEMM, f16, C = A.W^T + bias.  blockIdx.z in {0,1,2} = Q,K,V.
// z==2 epilogue: LDS transpose -> coalesced 16B Vt stores (two n-halves).
// ---------------------------------------------------------------------------
__global__ __launch_bounds__(256)
void qkv_gemm(const f16* __restrict__ A16, const f16* __restrict__ W16,
              const float* __restrict__ bq, const float* __restrict__ bk,
              const float* __restrict__ bv,
              f16* __restrict__ Qh, f16* __restrict__ Kh, f16* __restrict__ Vt)
{
    __shared__ __align__(16) char qsmem[16896];
    f16* const As = (f16*)qsmem;
    f16* const Bs = (f16*)(qsmem + 8192);
    f16* const Ct = (f16*)qsmem;              // [64 d][b*64+s], stride 132 (alias)

    const int tid  = threadIdx.x;
    const int w    = tid >> 6;
    const int lane = tid & 63;
    const int ln   = lane & 15;
    const int quad = lane >> 4;
    const int z  = blockIdx.z;
    const int m0 = blockIdx.x * 128;
    const int n0 = blockIdx.y * 128;
    const int wm = (w >> 1) * 64;
    const int wn = (w & 1) * 64;

    const f16* A = A16 + (size_t)z*MM*DD;
    const f16* W = W16 + (size_t)z*DD*DD;
    const float* bias = z == 0 ? bq : (z == 1 ? bk : bv);

    f32x4 acc[4][4];
    #pragma unroll
    for (int mt = 0; mt < 4; mt++)
        #pragma unroll
        for (int nt = 0; nt < 4; nt++)
            acc[mt][nt] = (f32x4){0.f,0.f,0.f,0.f};

    int slot[2], r_[2], gch[2];
    #pragma unroll
    for (int i = 0; i < 2; i++) {
        slot[i] = i*256 + tid;
        r_[i]   = slot[i] >> 2;
        gch[i]  = ((slot[i] & 3) ^ ((r_[i] >> 1) & 3)) * 8;
    }

    for (int step = 0; step < DD/32; step++) {
        const int k0 = step*32;
        __syncthreads();
        #pragma unroll
        for (int i = 0; i < 2; i++) {
            gload_lds16(A + (size_t)(m0 + r_[i])*DD + k0 + gch[i],
                        (char*)As + slot[i]*16);
            gload_lds16(W + (size_t)(n0 + r_[i])*DD + k0 + gch[i],
                        (char*)Bs + slot[i]*16);
        }
        __syncthreads();

        f16x8 af[4], bf[4];
        #pragma unroll
        for (int mt = 0; mt < 4; mt++) {
            int r = wm + mt*16 + ln;
            af[mt] = *(const f16x8*)&As[r*32 + ((quad ^ ((r>>1)&3)) << 3)];
        }
        #pragma unroll
        for (int nt = 0; nt < 4; nt++) {
            int r = wn + nt*16 + ln;
            bf[nt] = *(const f16x8*)&Bs[r*32 + ((quad ^ ((r>>1)&3)) << 3)];
        }
        #pragma unroll
        for (int mt = 0; mt < 4; mt++)
            #pragma unroll
            for (int nt = 0; nt < 4; nt++)
                acc[mt][nt] = __builtin_amdgcn_mfma_f32_16x16x32_f16(
                    af[mt], bf[nt], acc[mt][nt], 0, 0, 0);
    }

    float bvv[4];
    #pragma unroll
    for (int nt = 0; nt < 4; nt++) bvv[nt] = bias[n0 + wn + nt*16 + ln];

    if (z == 2) {
        // LDS transpose epilogue, one n-half (=head) at a time.
        #pragma unroll
        for (int half = 0; half < 2; half++) {
            __syncthreads();
            if ((wn >> 6) == half) {
                #pragma unroll
                for (int mt = 0; mt < 4; mt++)
                    #pragma unroll
                    for (int nt = 0; nt < 4; nt++)
                        #pragma unroll
                        for (int r = 0; r < 4; r++) {
                            int d = nt*16 + ln;
                            int sl = (wm >> 1) + mt*8 + quad*2 + (r >> 1);
                            Ct[d*132 + (r&1)*64 + sl] =
                                (f16)(acc[mt][nt][r] + bvv[nt]);
                        }
            }
            __syncthreads();
            {
                int d   = tid >> 2;
                int bb2 = (tid >> 1) & 1;
                int seg = tid & 1;
                int hh  = (n0 >> 6) + half;
                const f16* srcp = &Ct[d*132 + bb2*64 + seg*32];
                f16* dstp = Vt + ((size_t)(bb2*HH + hh)*DKK + d)*SS
                               + (m0 >> 1) + seg*32;
                #pragma unroll
                for (int k2 = 0; k2 < 4; k2++) {
                    uint2 a = *(const uint2*)(srcp + k2*8);
                    uint2 c = *(const uint2*)(srcp + k2*8 + 4);
                    uint4 u; u.x = a.x; u.y = a.y; u.z = c.x; u.w = c.y;
                    *(uint4*)(dstp + k2*8) = u;
                }
            }
        }
    } else {
        const float scale = z == 0 ? 0.125f : 1.0f;
        f16* dst = z == 0 ? Qh : Kh;
        #pragma unroll
        for (int mt = 0; mt < 4; mt++)
            #pragma unroll
            for (int nt = 0; nt < 4; nt++)
                #pragma unroll
                for (int r = 0; r < 4; r++) {
                    int m = m0 + wm + mt*16 + quad*4 + r;
                    int n = n0 + wn + nt*16 + ln;
                    int s = m >> 1, b = m & 1;
                    int h = n >> 6, d = n & 63;
                    dst[(((size_t)(b*HH + h))*SS + s)*DKK + d] =
                        (f16)((acc[mt][nt][r] + bvv[nt]) * scale);
                }
    }
}

// ---------------------------------------------------------------------------
// Output projection (unchanged).
// ---------------------------------------------------------------------------
__global__ __launch_bounds__(256)
void out_gemm(const f16* __restrict__ A, const f16* __restrict__ W,
              const float* __restrict__ bias, float* __restrict__ out)
{
    __shared__ __align__(16) f16 As[64*32];
    __shared__ __align__(16) f16 Bs[128*32];

    const int tid  = threadIdx.x;
    const int w    = tid >> 6;
    const int lane = tid & 63;
    const int ln   = lane & 15;
    const int quad = lane >> 4;
    const int m0 = blockIdx.x * 64;
    const int n0 = blockIdx.y * 128;
    const int wm = (w >> 1) * 32;
    const int wn = (w & 1) * 64;

    f32x4 acc[2][4];
    #pragma unroll
    for (int mt = 0; mt < 2; mt++)
        #pragma unroll
        for (int nt = 0; nt < 4; nt++)
            acc[mt][nt] = (f32x4){0.f,0.f,0.f,0.f};

    const int rA  = tid >> 2;
    const int gchA = ((tid & 3) ^ ((rA >> 1) & 3)) * 8;
    int slotB[2], rB[2], gchB[2];
    #pragma unroll
    for (int i = 0; i < 2; i++) {
        slotB[i] = i*256 + tid;
        rB[i]    = slotB[i] >> 2;
        gchB[i]  = ((slotB[i] & 3) ^ ((rB[i] >> 1) & 3)) * 8;
    }

    for (int step = 0; step < DD/32; step++) {
        const int k0 = step*32;
        __syncthreads();
        gload_lds16(A + (size_t)(m0 + rA)*DD + k0 + gchA, (char*)As + tid*16);
        #pragma unroll
        for (int i = 0; i < 2; i++)
            gload_lds16(W + (size_t)(n0 + rB[i])*DD + k0 + gchB[i],
                        (char*)Bs + slotB[i]*16);
        __syncthreads();

        f16x8 af[2], bf[4];
        #pragma unroll
        for (int mt = 0; mt < 2; mt++) {
            int r = wm + mt*16 + ln;
            af[mt] = *(const f16x8*)&As[r*32 + ((quad ^ ((r>>1)&3)) << 3)];
        }
        #pragma unroll
        for (int nt = 0; nt < 4; nt++) {
            int r = wn + nt*16 + ln;
            bf[nt] = *(const f16x8*)&Bs[r*32 + ((quad ^ ((r>>1)&3)) << 3)];
        }
        #pragma unroll
        for (int mt = 0; mt < 2; mt++)
            #pragma unroll
            for (int nt = 0; nt < 4; nt++)
                acc[mt][nt] = __builtin_amdgcn_mfma_f32_16x16x32_f16(
                    af[mt], bf[nt], acc[mt][nt], 0, 0, 0);
    }

    #pragma unroll
    for (int nt = 0; nt < 4; nt++) {
        float bvv = bias[n0 + wn + nt*16 + ln];
        #pragma unroll
        for (int mt = 0; mt < 2; mt++)
            #pragma unroll
            for (int r = 0; r < 4; r++) {
                int m = m0 + wm + mt*16 + quad*4 + r;
                int n = n0 + wn + nt*16 + ln;
                out[(size_t)m*DD + n] = acc[mt][nt][r] + bvv;
            }
    }
}

// ---------------------------------------------------------------------------
// Attention v7b: identical structure to v7 but NO min-waves occupancy cap
// (round 8's (512,6) forced o/U/qf into scratch: VGPR 40 + 148MB spill).
// LDS 33.8KB -> 2 blocks/CU; VGPR ~90-112 fits at 4 waves/SIMD.
// ---------------------------------------------------------------------------
__global__ __launch_bounds__(512)
void attn_v7b(const f16* __restrict__ Q, const f16* __restrict__ K,
              const f16* __restrict__ V, f16* __restrict__ Xh)
{
    __shared__ __align__(16) char arena[33792];
    float* const Ol = (float*)arena;                 // [128][65] (combine, aliased)
    float* const Ls = (float*)(arena + 33280);       // [128]

    const int tid  = threadIdx.x;
    const int g    = tid >> 8;         // kv-split group
    const int wg   = tid >> 6;
    const int w4   = wg & 3;
    const int lane = tid & 63;
    const int l5   = lane & 31;
    const int hf   = lane >> 5;
    const int h = blockIdx.y, b = blockIdx.z;
    const size_t base = ((size_t)(b*HH + h)) * SS * DKK;
    const int Q0 = blockIdx.x * 128;
    const int q  = w4*32 + l5;

    f16x8 qf[4];
    #pragma unroll
    for (int ks = 0; ks < 4; ks++)
        qf[ks] = *(const f16x8*)(Q + base + (size_t)(Q0 + q)*DKK + ks*16 + hf*8);

    f32x16 o[2];
    o[0] = (f32x16)(0.f); o[1] = (f32x16)(0.f);
    float lsum = 0.f;
    fp16x2r one2; one2[0] = (__fp16)1.0f; one2[1] = (__fp16)1.0f;

    const f16* const Ksg = (const f16*)(arena + g*8192);
    const f16* const Vsg = (const f16*)(arena + 16384 + g*8192);

    for (int t = 0; t < 16; t++) {
        __syncthreads();
        #pragma unroll
        for (int i = 0; i < 4; i++) {
            int slot = i*512 + tid;          // 0..2047
            int kv   = slot >> 10;           // 0 K, 1 V
            int s    = (slot >> 9) & 1;      // stream
            int idx  = slot & 511;
            int r    = idx >> 3, c8 = idx & 7;
            int kts  = s*16 + t;
            const f16* src = kv == 0
                ? K + base + (size_t)(kts*64 + r)*DKK + ((c8 ^ (r&7)) << 3)
                : V + base + (size_t)r*SS + kts*64 + ((c8 ^ (r&7)) << 3);
            gload_lds16(src, arena + kv*16384 + s*8192 + idx*16);
        }
        __syncthreads();

        // ---- S^T = K @ Q^T, per mt pass; exp + pack + row-sum ----
        unsigned U[2][4][2];
        #pragma unroll
        for (int mt = 0; mt < 2; mt++) {
            f32x16 sc = (f32x16)(0.f);
            #pragma unroll
            for (int ks = 0; ks < 4; ks++) {
                const int cc = ks*2 + hf;
                int key = mt*32 + l5;
                f16x8 ka = *(const f16x8*)&Ksg[key*64 + ((cc ^ (key&7)) << 3)];
                sc = __builtin_amdgcn_mfma_f32_32x32x16_f16(ka, qf[ks], sc, 0, 0, 0);
            }
            #pragma unroll
            for (int gg = 0; gg < 4; gg++) {
                unsigned u0 = pk2(__expf(sc[gg*4+0]), __expf(sc[gg*4+1]));
                unsigned u1 = pk2(__expf(sc[gg*4+2]), __expf(sc[gg*4+3]));
                U[mt][gg][0] = u0;
                U[mt][gg][1] = u1;
                union { unsigned u; fp16x2r h; } c0, c1;
                c0.u = u0; c1.u = u1;
                lsum = __builtin_amdgcn_fdot2(c0.h, one2, lsum, false);
                lsum = __builtin_amdgcn_fdot2(c1.h, one2, lsum, false);
            }
        }

        // ---- exchange -> PV B-frags; O^T += Vt @ P ----
        #pragma unroll
        for (int ks = 0; ks < 4; ks++) {
            const int mt0 = ks >> 1;
            const int e   = (ks & 1) * 2;
            unsigned k0 = hf ? U[mt0][e+1][0] : U[mt0][e][0];
            unsigned k1 = hf ? U[mt0][e+1][1] : U[mt0][e][1];
            unsigned s0 = hf ? U[mt0][e][0]   : U[mt0][e+1][0];
            unsigned s1 = hf ? U[mt0][e][1]   : U[mt0][e+1][1];
            unsigned r0 = __shfl_xor(s0, 32, 64);
            unsigned r1 = __shfl_xor(s1, 32, 64);
            union { unsigned u[4]; f16x8 v; } pbu;
            pbu.u[0] = hf ? r0 : k0;
            pbu.u[1] = hf ? r1 : k1;
            pbu.u[2] = hf ? k0 : r0;
            pbu.u[3] = hf ? k1 : r1;
            f16x8 pb = pbu.v;
            const int cc = ks*2 + hf;
            #pragma unroll
            for (int mt = 0; mt < 2; mt++) {
                int d = mt*32 + l5;
                f16x8 va = *(const f16x8*)&Vsg[d*64 + ((cc ^ (d&7)) << 3)];
                o[mt] = __builtin_amdgcn_mfma_f32_32x32x16_f16(va, pb, o[mt], 0, 0, 0);
            }
        }
    }

    // column total for q over this group's keys (both hf halves)
    float lfull = lsum + __shfl_xor(lsum, 32, 64);

    // ---- combine: g1 parks partials (arena dead), g0 reduces + writes ----
    __syncthreads();
    if (g == 1) {
        #pragma unroll
        for (int mt = 0; mt < 2; mt++)
            #pragma unroll
            for (int reg = 0; reg < 16; reg++) {
                int d = mt*32 + (reg & 3) + 8*(reg >> 2) + 4*hf;
                Ol[q*65 + d] = o[mt][reg];
            }
        if (hf == 0) Ls[q] = lfull;
    }
    __syncthreads();
    if (g == 0) {
        const float inv = 1.0f / (lfull + Ls[q]);
        const int qg = Q0 + q;
        f16* xp = Xh + ((size_t)qg*BB + b)*DD + h*DKK;
        #pragma unroll
        for (int mt = 0; mt < 2; mt++)
            #pragma unroll
            for (int gg = 0; gg < 4; gg++) {
                float v0 = (o[mt][gg*4+0] + Ol[q*65 + mt*32 + 8*gg + 4*hf + 0]) * inv;
                float v1 = (o[mt][gg*4+1] + Ol[q*65 + mt*32 + 8*gg + 4*hf + 1]) * inv;
                float v2 = (o[mt][gg*4+2] + Ol[q*65 + mt*32 + 8*gg + 4*hf + 2]) * inv;
                float v3 = (o[mt][gg*4+3] + Ol[q*65 + mt*32 + 8*gg + 4*hf + 3]) * inv;
                uint2 pk;
                pk.x = pk2(v0, v1);
                pk.y = pk2(v2, v3);
                *(uint2*)&xp[mt*32 + gg*8 + hf*4] = pk;
            }
    }
}

// ---------------------------------------------------------------------------
extern "C" void kernel_launch(void* const* d_in, const int* in_sizes, int n_in,
                              void* d_out, int out_size, void* d_ws, size_t ws_size,
                              hipStream_t stream) {
    (void)in_sizes; (void)n_in; (void)out_size; (void)ws_size;
    const float* query = (const float*)d_in[0];
    const float* key   = (const float*)d_in[1];
    const float* value = (const float*)d_in[2];
    const float* Wq = (const float*)d_in[3];
    const float* bq = (const float*)d_in[4];
    const float* Wk = (const float*)d_in[5];
    const float* bk = (const float*)d_in[6];
    const float* Wv = (const float*)d_in[7];
    const float* bv = (const float*)d_in[8];
    const float* Wo = (const float*)d_in[9];
    const float* bo = (const float*)d_in[10];

    char* ws = (char*)d_ws;
    f16* A16 = (f16*)ws;                          // 3 x 4096x1024 f16
    f16* W16 = (f16*)(ws + 25165824);             // 4 x 1024x1024 f16
    f16* Qh  = (f16*)(ws + 33554432);
    f16* Kh  = (f16*)(ws + 41943040);
    f16* Vt  = (f16*)(ws + 50331648);
    f16* Xh  = (f16*)(ws + 58720256);             // total 64 MiB

    cvt_all<<<dim3(MM*DD/8/256, 7), 256, 0, stream>>>(
        query, key, value, Wq, Wk, Wv, Wo, A16, W16);

    qkv_gemm<<<dim3(MM/128, DD/128, 3), 256, 0, stream>>>(
        A16, W16, bq, bk, bv, Qh, Kh, Vt);

    attn_v7b<<<dim3(SS/128, HH, BB), 512, 0, stream>>>(Qh, Kh, Vt, Xh);

    out_gemm<<<dim3(MM/64, DD/128), 256, 0, stream>>>(
        Xh, W16 + (size_t)3*DD*DD, bo, (float*)d_out);
}